// Round 7
// baseline (315.399 us; speedup 1.0000x reference)
//
#include <hip/hip_runtime.h>

// EPN layer: B=8, N=256, DH=32, DX=3, DQ=1, DE=8, H1=H2=32, DIN=80.
// layer1 = relu(Pa[i] + Pb'[j] + e_ij@W1e), Pb' has b1 folded in.
// b3 cancels in 0.5*(elec_ij - elec_ji).
//
// R1: remat. R3: fission. R5: AGPR-forced accs + spilled atom_proj.
// R6: MFMA layer-2 via LDS-staged Z: PASSED (absmax .25) -> 32x32x16 bf16
//     A/B/C fragment mappings hardware-validated. pair ~35us, limited by
//     barrier stalls at 3 blocks/CU (43.5 KB LDS).
// R7: k-split restructure: thread (lo,h) computes z exactly for its B-frag
//     elements (k = {h*8+t, 16+h*8+t}, j = 64w+32*st+lo) -> z goes
//     register->MFMA. No Z LDS, no block barrier (except final 16B reduce).
//     W1e/Pi reads are per-half-uniform (broadcast-coalesced). st-tiles
//     sequenced so only one acc pair (32 regs) is live.

#define NATOM 256
#define TOT_ATOMS 2048

typedef __bf16 bf16x8 __attribute__((ext_vector_type(8)));
typedef float  f32x16 __attribute__((ext_vector_type(16)));

// ---- Kernel A: per-atom projections, P[atom][64]: c<32 = Pa, c>=32 = Pb+b1.
__global__ __launch_bounds__(256) void atom_proj_kernel(
    const float* __restrict__ x, const float* __restrict__ h,
    const float* __restrict__ q, const float* __restrict__ W1,
    const float* __restrict__ b1, float* __restrict__ P)
{
    const int a  = threadIdx.x >> 5;   // 0..7
    const int u  = threadIdx.x & 31;   // 0..31
    const int n0 = blockIdx.x * 8;

    __shared__ float sd[8][37];        // x(3), h(32), q(1), pad
    for (int idx = threadIdx.x; idx < 8 * 36; idx += 256) {
        const int aa = idx / 36, r = idx - aa * 36;
        const int n = n0 + aa;
        float v;
        if (r < 3)       v = x[n * 3 + r];
        else if (r < 35) v = h[n * 32 + (r - 3)];
        else             v = q[n];
        sd[aa][r] = v;
    }
    __syncthreads();

    float pa = 0.f, pb = b1[u];
#pragma unroll
    for (int r = 0; r < 36; ++r) {
        const float d = sd[a][r];
        pa += d * W1[r * 32 + u];
        pb += d * W1[(36 + r) * 32 + u];
    }
    const int n = n0 + a;
    P[(size_t)n * 64 + u]      = pa;
    P[(size_t)n * 64 + 32 + u] = pb;
}

// ---- Kernel B: one block per (b,i) row; barrier-free MFMA pipeline.
__global__ __launch_bounds__(256, 4) void pair_kernel(
    const float* __restrict__ e, const float* __restrict__ mask,
    const float* __restrict__ q, const float* __restrict__ P,
    const float* __restrict__ W1, const float* __restrict__ W2,
    const float* __restrict__ b2, const float* __restrict__ W3,
    float* __restrict__ out)
{
    const int row  = blockIdx.x;       // b*256 + i == atom index of i
    const int b    = row >> 8;
    const int tid  = threadIdx.x;
    const int wave = tid >> 6;
    const int lane = tid & 63;
    const int lo   = lane & 31;        // MFMA m/n index
    const int h    = lane >> 5;        // MFMA k-half

    // A-fragments: A[m=u=lo][k] = W2[k][lo]; k = kb*16 + h*8 + t. st-invariant.
    bf16x8 A0, A1;
#pragma unroll
    for (int t = 0; t < 8; ++t) {
        A0[t] = (__bf16)W2[(h * 8 + t) * 32 + lo];
        A1[t] = (__bf16)W2[(16 + h * 8 + t) * 32 + lo];
    }

    const float* Pi = P + (size_t)row * 64;   // per-half-uniform -> broadcast
    __shared__ float red[4];
    float vacc = 0.f;

#pragma unroll
    for (int st = 0; st < 2; ++st) {
        const int j    = (wave << 6) + (st << 5) + lo;   // this lane's B-column
        const int colj = (b << 8) + j;
        const float* Pj = P + (size_t)colj * 64;

        // e row + gate for this j
        const float* ep = e + ((size_t)row * NATOM + j) * 8;
        float e8[8];
        *(float4*)&e8[0] = ((const float4*)ep)[0];
        *(float4*)&e8[4] = ((const float4*)ep)[1];
        const float m = mask[row * NATOM + j];
        float mx = e8[0];
#pragma unroll
        for (int k = 1; k < 8; ++k) mx = fmaxf(mx, e8[k]);
        const float g = (mx > 1e-5f) ? 0.5f * m : 0.f;

        f32x16 cij = {0.f}, cji = {0.f};
#pragma unroll
        for (int kb = 0; kb < 2; ++kb) {
            const int k0 = kb * 16 + h * 8;   // this lane's 8 k's for this kb
            // P slices (Pi: broadcast per half; Pj: per-lane, L2-resident)
            const float4 pai0 = *(const float4*)(Pi + k0);
            const float4 pai1 = *(const float4*)(Pi + k0 + 4);
            const float4 pbi0 = *(const float4*)(Pi + 32 + k0);
            const float4 pbi1 = *(const float4*)(Pi + 32 + k0 + 4);
            const float4 paj0 = *(const float4*)(Pj + k0);
            const float4 paj1 = *(const float4*)(Pj + k0 + 4);
            const float4 pbj0 = *(const float4*)(Pj + 32 + k0);
            const float4 pbj1 = *(const float4*)(Pj + 32 + k0 + 4);

            // ez[t] = sum_de e8[de] * W1e[de][k0+t]  (W1e loads broadcast/half)
            float ez[8] = {0.f, 0.f, 0.f, 0.f, 0.f, 0.f, 0.f, 0.f};
#pragma unroll
            for (int de = 0; de < 8; ++de) {
                const float ev = e8[de];
                const float4 wa = *(const float4*)(W1 + (72 + de) * 32 + k0);
                const float4 wb = *(const float4*)(W1 + (72 + de) * 32 + k0 + 4);
                ez[0] += ev * wa.x; ez[1] += ev * wa.y;
                ez[2] += ev * wa.z; ez[3] += ev * wa.w;
                ez[4] += ev * wb.x; ez[5] += ev * wb.y;
                ez[6] += ev * wb.z; ez[7] += ev * wb.w;
            }

            // z for exactly this lane's B-fragment elements
            bf16x8 Bij, Bji;
#pragma unroll
            for (int t = 0; t < 8; ++t) {
                const float pai = (t < 4) ? ((const float*)&pai0)[t] : ((const float*)&pai1)[t - 4];
                const float pbi = (t < 4) ? ((const float*)&pbi0)[t] : ((const float*)&pbi1)[t - 4];
                const float paj = (t < 4) ? ((const float*)&paj0)[t] : ((const float*)&paj1)[t - 4];
                const float pbj = (t < 4) ? ((const float*)&pbj0)[t] : ((const float*)&pbj1)[t - 4];
                const float zij = fmaxf(pai + pbj + ez[t], 0.f);
                const float zji = fmaxf(paj + pbi + ez[t], 0.f);
                Bij[t] = (__bf16)zij;
                Bji[t] = (__bf16)zji;
            }
            if (kb == 0) {
                cij = __builtin_amdgcn_mfma_f32_32x32x16_bf16(A0, Bij, cij, 0, 0, 0);
                cji = __builtin_amdgcn_mfma_f32_32x32x16_bf16(A0, Bji, cji, 0, 0, 0);
            } else {
                cij = __builtin_amdgcn_mfma_f32_32x32x16_bf16(A1, Bij, cij, 0, 0, 0);
                cji = __builtin_amdgcn_mfma_f32_32x32x16_bf16(A1, Bji, cji, 0, 0, 0);
            }
        }

        // epilogue: C col = j (=lo-col), rows u = (reg&3)+8*(reg>>2)+4h
        float d = 0.f;
#pragma unroll
        for (int reg = 0; reg < 16; ++reg) {
            const int u0 = (reg & 3) + 8 * (reg >> 2);
            const float b2v = h ? b2[u0 + 4] : b2[u0];
            const float w3v = h ? W3[u0 + 4] : W3[u0];
            const float rij = fmaxf(cij[reg] + b2v, 0.f);
            const float rji = fmaxf(cji[reg] + b2v, 0.f);
            d += (rij - rji) * w3v;
        }
        d += __shfl_xor(d, 32, 64);   // complete the 32-u sum across halves
        vacc += d * g;
    }

    // wave sum (each j counted in both halves -> x2), then block sum
#pragma unroll
    for (int off = 1; off < 64; off <<= 1)
        vacc += __shfl_xor(vacc, off, 64);
    if (lane == 0) red[wave] = vacc;
    __syncthreads();
    if (tid == 0)
        out[row] = q[row] + 0.5f * (red[0] + red[1] + red[2] + red[3]);
}

extern "C" void kernel_launch(void* const* d_in, const int* in_sizes, int n_in,
                              void* d_out, int out_size, void* d_ws, size_t ws_size,
                              hipStream_t stream)
{
    const float* h    = (const float*)d_in[0];
    const float* e    = (const float*)d_in[1];
    const float* x    = (const float*)d_in[2];
    const float* q    = (const float*)d_in[3];
    const float* mask = (const float*)d_in[4];
    const float* W1   = (const float*)d_in[5];
    const float* b1   = (const float*)d_in[6];
    const float* W2   = (const float*)d_in[7];
    const float* b2   = (const float*)d_in[8];
    const float* W3   = (const float*)d_in[9];
    // b3 cancels in the antisymmetric difference.

    float* P = (float*)d_ws;  // [2048][64] floats = 512 KB

    atom_proj_kernel<<<256, 256, 0, stream>>>(x, h, q, W1, b1, P);
    pair_kernel<<<TOT_ATOMS, 256, 0, stream>>>(e, mask, q, P, W1, W2, b2, W3,
                                               (float*)d_out);
}

// Round 8
// 182.421 us; speedup vs baseline: 1.7290x; 1.7290x over previous
//
#include <hip/hip_runtime.h>

// EPN layer: B=8, N=256, DH=32, DX=3, DQ=1, DE=8, H1=H2=32, DIN=80.
// layer1 = relu(Pa[i] + Pb'[j] + e_ij@W1e), Pb' has b1 folded in.
// b3 cancels in 0.5*(elec_ij - elec_ji).
//
// R1: remat. R3: fission. R5: AGPR accs + spilled atom_proj.
// R6: MFMA layer-2 (LDS-staged Z) passed, pair ~35us (barrier-stalled).
// R7: barrier-free k-split passed numerically BUT regressed to 250us:
//     FETCH 253MB / WRITE 479MB scratch traffic. Cause: address-taken
//     locals (*(float4*)&e8[0], ((float*)&pai0)[t]) on struct float4
//     defeated SROA -> allocas in scratch. Fix: ext_vector_type f32x4
//     everywhere (extract/insertelement, no allocas); launch_bounds(256,3).

#define NATOM 256
#define TOT_ATOMS 2048

typedef __bf16 bf16x8 __attribute__((ext_vector_type(8)));
typedef float  f32x16 __attribute__((ext_vector_type(16)));
typedef float  f32x4  __attribute__((ext_vector_type(4)));

// ---- Kernel A: per-atom projections, P[atom][64]: c<32 = Pa, c>=32 = Pb+b1.
__global__ __launch_bounds__(256) void atom_proj_kernel(
    const float* __restrict__ x, const float* __restrict__ h,
    const float* __restrict__ q, const float* __restrict__ W1,
    const float* __restrict__ b1, float* __restrict__ P)
{
    const int a  = threadIdx.x >> 5;   // 0..7
    const int u  = threadIdx.x & 31;   // 0..31
    const int n0 = blockIdx.x * 8;

    __shared__ float sd[8][37];        // x(3), h(32), q(1), pad
    for (int idx = threadIdx.x; idx < 8 * 36; idx += 256) {
        const int aa = idx / 36, r = idx - aa * 36;
        const int n = n0 + aa;
        float v;
        if (r < 3)       v = x[n * 3 + r];
        else if (r < 35) v = h[n * 32 + (r - 3)];
        else             v = q[n];
        sd[aa][r] = v;
    }
    __syncthreads();

    float pa = 0.f, pb = b1[u];
#pragma unroll
    for (int r = 0; r < 36; ++r) {
        const float d = sd[a][r];
        pa += d * W1[r * 32 + u];
        pb += d * W1[(36 + r) * 32 + u];
    }
    const int n = n0 + a;
    P[(size_t)n * 64 + u]      = pa;
    P[(size_t)n * 64 + 32 + u] = pb;
}

// ---- Kernel B: one block per (b,i) row; barrier-free MFMA pipeline.
__global__ __launch_bounds__(256, 3) void pair_kernel(
    const float* __restrict__ e, const float* __restrict__ mask,
    const float* __restrict__ q, const float* __restrict__ P,
    const float* __restrict__ W1, const float* __restrict__ W2,
    const float* __restrict__ b2, const float* __restrict__ W3,
    float* __restrict__ out)
{
    const int row  = blockIdx.x;       // b*256 + i == atom index of i
    const int b    = row >> 8;
    const int tid  = threadIdx.x;
    const int wave = tid >> 6;
    const int lane = tid & 63;
    const int lo   = lane & 31;        // MFMA m/n index
    const int h    = lane >> 5;        // MFMA k-half

    // A-fragments: A[m=u=lo][k] = W2[k][lo]; k = kb*16 + h*8 + t. st-invariant.
    bf16x8 A0, A1;
#pragma unroll
    for (int t = 0; t < 8; ++t) {
        A0[t] = (__bf16)W2[(h * 8 + t) * 32 + lo];
        A1[t] = (__bf16)W2[(16 + h * 8 + t) * 32 + lo];
    }

    const float* Pi = P + (size_t)row * 64;
    __shared__ float red[4];
    float vacc = 0.f;

#pragma unroll
    for (int st = 0; st < 2; ++st) {
        const int j    = (wave << 6) + (st << 5) + lo;   // this lane's B-column
        const int colj = (b << 8) + j;
        const float* Pj = P + (size_t)colj * 64;

        // e row + gate for this j (native ext-vectors: no allocas)
        const float* ep = e + ((size_t)row * NATOM + j) * 8;
        const f32x4 ea = *(const f32x4*)(ep);
        const f32x4 eb = *(const f32x4*)(ep + 4);
        const float m = mask[row * NATOM + j];
        float mx = fmaxf(fmaxf(fmaxf(ea[0], ea[1]), fmaxf(ea[2], ea[3])),
                         fmaxf(fmaxf(eb[0], eb[1]), fmaxf(eb[2], eb[3])));
        const float g = (mx > 1e-5f) ? 0.5f * m : 0.f;

        f32x16 cij = {0.f}, cji = {0.f};
#pragma unroll
        for (int kb = 0; kb < 2; ++kb) {
            const int k0 = kb * 16 + h * 8;   // this lane's 8 k's for this kb
            const f32x4 pai0 = *(const f32x4*)(Pi + k0);
            const f32x4 pai1 = *(const f32x4*)(Pi + k0 + 4);
            const f32x4 pbi0 = *(const f32x4*)(Pi + 32 + k0);
            const f32x4 pbi1 = *(const f32x4*)(Pi + 32 + k0 + 4);
            const f32x4 paj0 = *(const f32x4*)(Pj + k0);
            const f32x4 paj1 = *(const f32x4*)(Pj + k0 + 4);
            const f32x4 pbj0 = *(const f32x4*)(Pj + 32 + k0);
            const f32x4 pbj1 = *(const f32x4*)(Pj + 32 + k0 + 4);

            // ez = sum_de e8[de] * W1e[de][k0..k0+7]  (vector FMAs)
            f32x4 eza = {0.f, 0.f, 0.f, 0.f};
            f32x4 ezb = {0.f, 0.f, 0.f, 0.f};
#pragma unroll
            for (int de = 0; de < 8; ++de) {
                const float ev = (de < 4) ? ea[de & 3] : eb[de & 3];
                const f32x4 wa = *(const f32x4*)(W1 + (72 + de) * 32 + k0);
                const f32x4 wb = *(const f32x4*)(W1 + (72 + de) * 32 + k0 + 4);
                eza += wa * ev;
                ezb += wb * ev;
            }

            // z for exactly this lane's B-fragment elements
            bf16x8 Bij, Bji;
#pragma unroll
            for (int t = 0; t < 4; ++t) {
                Bij[t]     = (__bf16)fmaxf(pai0[t] + pbj0[t] + eza[t], 0.f);
                Bji[t]     = (__bf16)fmaxf(paj0[t] + pbi0[t] + eza[t], 0.f);
                Bij[t + 4] = (__bf16)fmaxf(pai1[t] + pbj1[t] + ezb[t], 0.f);
                Bji[t + 4] = (__bf16)fmaxf(paj1[t] + pbi1[t] + ezb[t], 0.f);
            }
            if (kb == 0) {
                cij = __builtin_amdgcn_mfma_f32_32x32x16_bf16(A0, Bij, cij, 0, 0, 0);
                cji = __builtin_amdgcn_mfma_f32_32x32x16_bf16(A0, Bji, cji, 0, 0, 0);
            } else {
                cij = __builtin_amdgcn_mfma_f32_32x32x16_bf16(A1, Bij, cij, 0, 0, 0);
                cji = __builtin_amdgcn_mfma_f32_32x32x16_bf16(A1, Bji, cji, 0, 0, 0);
            }
        }

        // epilogue: C col = j (=lo), rows u = (reg&3)+8*(reg>>2)+4h
        float d = 0.f;
#pragma unroll
        for (int reg = 0; reg < 16; ++reg) {
            const int u0 = (reg & 3) + 8 * (reg >> 2);
            const float b2v = h ? b2[u0 + 4] : b2[u0];
            const float w3v = h ? W3[u0 + 4] : W3[u0];
            const float rij = fmaxf(cij[reg] + b2v, 0.f);
            const float rji = fmaxf(cji[reg] + b2v, 0.f);
            d += (rij - rji) * w3v;
        }
        d += __shfl_xor(d, 32, 64);   // complete the 32-u sum across halves
        vacc += d * g;
    }

    // wave sum (each j counted in both halves -> x2), then block sum
#pragma unroll
    for (int off = 1; off < 64; off <<= 1)
        vacc += __shfl_xor(vacc, off, 64);
    if (lane == 0) red[wave] = vacc;
    __syncthreads();
    if (tid == 0)
        out[row] = q[row] + 0.5f * (red[0] + red[1] + red[2] + red[3]);
}

extern "C" void kernel_launch(void* const* d_in, const int* in_sizes, int n_in,
                              void* d_out, int out_size, void* d_ws, size_t ws_size,
                              hipStream_t stream)
{
    const float* h    = (const float*)d_in[0];
    const float* e    = (const float*)d_in[1];
    const float* x    = (const float*)d_in[2];
    const float* q    = (const float*)d_in[3];
    const float* mask = (const float*)d_in[4];
    const float* W1   = (const float*)d_in[5];
    const float* b1   = (const float*)d_in[6];
    const float* W2   = (const float*)d_in[7];
    const float* b2   = (const float*)d_in[8];
    const float* W3   = (const float*)d_in[9];
    // b3 cancels in the antisymmetric difference.

    float* P = (float*)d_ws;  // [2048][64] floats = 512 KB

    atom_proj_kernel<<<256, 256, 0, stream>>>(x, h, q, W1, b1, P);
    pair_kernel<<<TOT_ATOMS, 256, 0, stream>>>(e, mask, q, P, W1, W2, b2, W3,
                                               (float*)d_out);
}

// Round 9
// 173.806 us; speedup vs baseline: 1.8147x; 1.0496x over previous
//
#include <hip/hip_runtime.h>

// EPN layer: B=8, N=256, DH=32, DX=3, DQ=1, DE=8, H1=H2=32, DIN=80.
// layer1 = relu(Pa[i] + Pb'[j] + e_ij@W1e), Pb' has b1 folded in.
// b3 cancels in 0.5*(elec_ij - elec_ji).
//
// R1: remat. R3: fission. R5: AGPR accs + spilled atom_proj.
// R6: MFMA layer-2 (LDS Z staging): clean, pair ~35us.
// R7/R8: barrier-free k-split correct but scratch-bound (479->203 MB writes).
//   Cause isolated by A/B across rounds: element-wise insertion into __bf16
//   ext-vectors (A0[t]=..., Bij[t]=...) lowers through an alloca that SROA
//   misses -> private-memory traffic. R6's integer pk2 path was clean.
// R9: all bf16 fragments built as u32x4 vector literals of pk2() then
//   bit_cast to bf16x8. No bf16 vector subscript-assign anywhere.

#define NATOM 256
#define TOT_ATOMS 2048

typedef __bf16 bf16x8 __attribute__((ext_vector_type(8)));
typedef float  f32x16 __attribute__((ext_vector_type(16)));
typedef float  f32x4  __attribute__((ext_vector_type(4)));
typedef unsigned int u32x4 __attribute__((ext_vector_type(4)));

__device__ __forceinline__ unsigned int pk2(float a, float b) {
    unsigned short lo = __builtin_bit_cast(unsigned short, (__bf16)a);
    unsigned short hi = __builtin_bit_cast(unsigned short, (__bf16)b);
    return (unsigned int)lo | ((unsigned int)hi << 16);
}

// ---- Kernel A: per-atom projections, P[atom][64]: c<32 = Pa, c>=32 = Pb+b1.
__global__ __launch_bounds__(256) void atom_proj_kernel(
    const float* __restrict__ x, const float* __restrict__ h,
    const float* __restrict__ q, const float* __restrict__ W1,
    const float* __restrict__ b1, float* __restrict__ P)
{
    const int a  = threadIdx.x >> 5;   // 0..7
    const int u  = threadIdx.x & 31;   // 0..31
    const int n0 = blockIdx.x * 8;

    __shared__ float sd[8][37];        // x(3), h(32), q(1), pad
    for (int idx = threadIdx.x; idx < 8 * 36; idx += 256) {
        const int aa = idx / 36, r = idx - aa * 36;
        const int n = n0 + aa;
        float v;
        if (r < 3)       v = x[n * 3 + r];
        else if (r < 35) v = h[n * 32 + (r - 3)];
        else             v = q[n];
        sd[aa][r] = v;
    }
    __syncthreads();

    float pa = 0.f, pb = b1[u];
#pragma unroll
    for (int r = 0; r < 36; ++r) {
        const float d = sd[a][r];
        pa += d * W1[r * 32 + u];
        pb += d * W1[(36 + r) * 32 + u];
    }
    const int n = n0 + a;
    P[(size_t)n * 64 + u]      = pa;
    P[(size_t)n * 64 + 32 + u] = pb;
}

// ---- Kernel B: one block per (b,i) row; barrier-free MFMA pipeline.
__global__ __launch_bounds__(256, 3) void pair_kernel(
    const float* __restrict__ e, const float* __restrict__ mask,
    const float* __restrict__ q, const float* __restrict__ P,
    const float* __restrict__ W1, const float* __restrict__ W2,
    const float* __restrict__ b2, const float* __restrict__ W3,
    float* __restrict__ out)
{
    const int row  = blockIdx.x;       // b*256 + i == atom index of i
    const int b    = row >> 8;
    const int tid  = threadIdx.x;
    const int wave = tid >> 6;
    const int lane = tid & 63;
    const int lo   = lane & 31;        // MFMA m/n index
    const int h    = lane >> 5;        // MFMA k-half

    // A-fragments: A[m=u=lo][k] = W2[k][lo]; k = kb*16 + h*8 + t.
    const int kA = h * 8;
    const u32x4 a0w = { pk2(W2[(kA + 0) * 32 + lo], W2[(kA + 1) * 32 + lo]),
                        pk2(W2[(kA + 2) * 32 + lo], W2[(kA + 3) * 32 + lo]),
                        pk2(W2[(kA + 4) * 32 + lo], W2[(kA + 5) * 32 + lo]),
                        pk2(W2[(kA + 6) * 32 + lo], W2[(kA + 7) * 32 + lo]) };
    const u32x4 a1w = { pk2(W2[(16 + kA + 0) * 32 + lo], W2[(16 + kA + 1) * 32 + lo]),
                        pk2(W2[(16 + kA + 2) * 32 + lo], W2[(16 + kA + 3) * 32 + lo]),
                        pk2(W2[(16 + kA + 4) * 32 + lo], W2[(16 + kA + 5) * 32 + lo]),
                        pk2(W2[(16 + kA + 6) * 32 + lo], W2[(16 + kA + 7) * 32 + lo]) };
    const bf16x8 A0 = __builtin_bit_cast(bf16x8, a0w);
    const bf16x8 A1 = __builtin_bit_cast(bf16x8, a1w);

    const float* Pi = P + (size_t)row * 64;
    __shared__ float red[4];
    float vacc = 0.f;

#pragma unroll
    for (int st = 0; st < 2; ++st) {
        const int j    = (wave << 6) + (st << 5) + lo;   // this lane's B-column
        const int colj = (b << 8) + j;
        const float* Pj = P + (size_t)colj * 64;

        // e row + gate for this j
        const float* ep = e + ((size_t)row * NATOM + j) * 8;
        const f32x4 ea = *(const f32x4*)(ep);
        const f32x4 eb = *(const f32x4*)(ep + 4);
        const float m = mask[row * NATOM + j];
        float mx = fmaxf(fmaxf(fmaxf(ea[0], ea[1]), fmaxf(ea[2], ea[3])),
                         fmaxf(fmaxf(eb[0], eb[1]), fmaxf(eb[2], eb[3])));
        const float g = (mx > 1e-5f) ? 0.5f * m : 0.f;

        f32x16 cij = {0.f}, cji = {0.f};
#pragma unroll
        for (int kb = 0; kb < 2; ++kb) {
            const int k0 = kb * 16 + h * 8;   // this lane's 8 k's for this kb
            const f32x4 pai0 = *(const f32x4*)(Pi + k0);
            const f32x4 pai1 = *(const f32x4*)(Pi + k0 + 4);
            const f32x4 pbi0 = *(const f32x4*)(Pi + 32 + k0);
            const f32x4 pbi1 = *(const f32x4*)(Pi + 32 + k0 + 4);
            const f32x4 paj0 = *(const f32x4*)(Pj + k0);
            const f32x4 paj1 = *(const f32x4*)(Pj + k0 + 4);
            const f32x4 pbj0 = *(const f32x4*)(Pj + 32 + k0);
            const f32x4 pbj1 = *(const f32x4*)(Pj + 32 + k0 + 4);

            // ez = sum_de e8[de] * W1e[de][k0..k0+7]  (vector FMAs)
            f32x4 eza = {0.f, 0.f, 0.f, 0.f};
            f32x4 ezb = {0.f, 0.f, 0.f, 0.f};
#pragma unroll
            for (int de = 0; de < 8; ++de) {
                const float ev = (de < 4) ? ea[de & 3] : eb[de & 3];
                const f32x4 wa = *(const f32x4*)(W1 + (72 + de) * 32 + k0);
                const f32x4 wb = *(const f32x4*)(W1 + (72 + de) * 32 + k0 + 4);
                eza += wa * ev;
                ezb += wb * ev;
            }

            // z for this lane's B-fragment elements; pack via integer path
            const f32x4 sij0 = pai0 + pbj0 + eza;
            const f32x4 sij1 = pai1 + pbj1 + ezb;
            const f32x4 sji0 = paj0 + pbi0 + eza;
            const f32x4 sji1 = paj1 + pbi1 + ezb;
            const u32x4 wij = {
                pk2(fmaxf(sij0[0], 0.f), fmaxf(sij0[1], 0.f)),
                pk2(fmaxf(sij0[2], 0.f), fmaxf(sij0[3], 0.f)),
                pk2(fmaxf(sij1[0], 0.f), fmaxf(sij1[1], 0.f)),
                pk2(fmaxf(sij1[2], 0.f), fmaxf(sij1[3], 0.f)) };
            const u32x4 wji = {
                pk2(fmaxf(sji0[0], 0.f), fmaxf(sji0[1], 0.f)),
                pk2(fmaxf(sji0[2], 0.f), fmaxf(sji0[3], 0.f)),
                pk2(fmaxf(sji1[0], 0.f), fmaxf(sji1[1], 0.f)),
                pk2(fmaxf(sji1[2], 0.f), fmaxf(sji1[3], 0.f)) };
            const bf16x8 Bij = __builtin_bit_cast(bf16x8, wij);
            const bf16x8 Bji = __builtin_bit_cast(bf16x8, wji);

            if (kb == 0) {
                cij = __builtin_amdgcn_mfma_f32_32x32x16_bf16(A0, Bij, cij, 0, 0, 0);
                cji = __builtin_amdgcn_mfma_f32_32x32x16_bf16(A0, Bji, cji, 0, 0, 0);
            } else {
                cij = __builtin_amdgcn_mfma_f32_32x32x16_bf16(A1, Bij, cij, 0, 0, 0);
                cji = __builtin_amdgcn_mfma_f32_32x32x16_bf16(A1, Bji, cji, 0, 0, 0);
            }
        }

        // epilogue: C col = j (=lo), rows u = (reg&3)+8*(reg>>2)+4h
        float d = 0.f;
#pragma unroll
        for (int reg = 0; reg < 16; ++reg) {
            const int u0 = (reg & 3) + 8 * (reg >> 2);
            const float b2v = h ? b2[u0 + 4] : b2[u0];
            const float w3v = h ? W3[u0 + 4] : W3[u0];
            const float rij = fmaxf(cij[reg] + b2v, 0.f);
            const float rji = fmaxf(cji[reg] + b2v, 0.f);
            d += (rij - rji) * w3v;
        }
        d += __shfl_xor(d, 32, 64);   // complete the 32-u sum across halves
        vacc += d * g;
    }

    // wave sum (each j counted in both halves -> x2), then block sum
#pragma unroll
    for (int off = 1; off < 64; off <<= 1)
        vacc += __shfl_xor(vacc, off, 64);
    if (lane == 0) red[wave] = vacc;
    __syncthreads();
    if (tid == 0)
        out[row] = q[row] + 0.5f * (red[0] + red[1] + red[2] + red[3]);
}

extern "C" void kernel_launch(void* const* d_in, const int* in_sizes, int n_in,
                              void* d_out, int out_size, void* d_ws, size_t ws_size,
                              hipStream_t stream)
{
    const float* h    = (const float*)d_in[0];
    const float* e    = (const float*)d_in[1];
    const float* x    = (const float*)d_in[2];
    const float* q    = (const float*)d_in[3];
    const float* mask = (const float*)d_in[4];
    const float* W1   = (const float*)d_in[5];
    const float* b1   = (const float*)d_in[6];
    const float* W2   = (const float*)d_in[7];
    const float* b2   = (const float*)d_in[8];
    const float* W3   = (const float*)d_in[9];
    // b3 cancels in the antisymmetric difference.

    float* P = (float*)d_ws;  // [2048][64] floats = 512 KB

    atom_proj_kernel<<<256, 256, 0, stream>>>(x, h, q, W1, b1, P);
    pair_kernel<<<TOT_ATOMS, 256, 0, stream>>>(e, mask, q, P, W1, W2, b2, W3,
                                               (float*)d_out);
}

// Round 10
// 135.354 us; speedup vs baseline: 2.3302x; 1.2841x over previous
//
#include <hip/hip_runtime.h>

// EPN layer: B=8, N=256, DH=32, DX=3, DQ=1, DE=8, H1=H2=32, DIN=80.
// layer1 = relu(Pa[i] + Pb'[j] + e_ij@W1e), Pb' has b1 folded in.
// b3 cancels in 0.5*(elec_ij - elec_ji).
//
// R1: remat. R3: fission. R5: AGPR accs + spilled atom_proj.
// R6: MFMA layer-2 with LDS-staged Z: proven fast (~35us) and correct.
// R7-9: barrier-free k-split correct but 100-250us wall; the 180-479MB
//   "scratch" traffic tracks the harness restore+poison volume (282MB/iter),
//   i.e. likely concurrent-fill pollution of the counter window + a
//   latency-starved gather structure. Abandoned.
// R10: R6 structure, improved: ZS 40->32 with XOR chunk swizzle (b128-safe,
//   <=4-way conflicts), W2t LDS dropped (A-frags via pk2 global gathers,
//   R9-validated), LDS 43.5->33.3KB -> 4 blocks/CU (16 waves/CU).

#define NATOM 256
#define TOT_ATOMS 2048
#define ZS 32   // ushorts per Z row (64 B); 16B chunks XOR-swizzled by (j>>1)&3

typedef __bf16 bf16x8 __attribute__((ext_vector_type(8)));
typedef float  f32x16 __attribute__((ext_vector_type(16)));
typedef float  f32x4  __attribute__((ext_vector_type(4)));
typedef unsigned int u32x2 __attribute__((ext_vector_type(2)));
typedef unsigned int u32x4 __attribute__((ext_vector_type(4)));

__device__ __forceinline__ unsigned int pk2(float a, float b) {
    unsigned short lo = __builtin_bit_cast(unsigned short, (__bf16)a);
    unsigned short hi = __builtin_bit_cast(unsigned short, (__bf16)b);
    return (unsigned int)lo | ((unsigned int)hi << 16);
}

// ---- Kernel A: per-atom projections, P[atom][64]: c<32 = Pa, c>=32 = Pb+b1.
__global__ __launch_bounds__(256) void atom_proj_kernel(
    const float* __restrict__ x, const float* __restrict__ h,
    const float* __restrict__ q, const float* __restrict__ W1,
    const float* __restrict__ b1, float* __restrict__ P)
{
    const int a  = threadIdx.x >> 5;   // 0..7
    const int u  = threadIdx.x & 31;   // 0..31
    const int n0 = blockIdx.x * 8;

    __shared__ float sd[8][37];        // x(3), h(32), q(1), pad
    for (int idx = threadIdx.x; idx < 8 * 36; idx += 256) {
        const int aa = idx / 36, r = idx - aa * 36;
        const int n = n0 + aa;
        float v;
        if (r < 3)       v = x[n * 3 + r];
        else if (r < 35) v = h[n * 32 + (r - 3)];
        else             v = q[n];
        sd[aa][r] = v;
    }
    __syncthreads();

    float pa = 0.f, pb = b1[u];
#pragma unroll
    for (int r = 0; r < 36; ++r) {
        const float d = sd[a][r];
        pa += d * W1[r * 32 + u];
        pb += d * W1[(36 + r) * 32 + u];
    }
    const int n = n0 + a;
    P[(size_t)n * 64 + u]      = pa;
    P[(size_t)n * 64 + 32 + u] = pb;
}

// ---- Kernel B: one block per (b,i) row; layer-1 VALU -> swizzled bf16 Z in
//      LDS -> MFMA layer-2 -> per-lane epilogue.
__global__ __launch_bounds__(256, 4) void pair_kernel(
    const float* __restrict__ e, const float* __restrict__ mask,
    const float* __restrict__ q, const float* __restrict__ P,
    const float* __restrict__ W1, const float* __restrict__ W2,
    const float* __restrict__ b2, const float* __restrict__ W3,
    float* __restrict__ out)
{
    const int row = blockIdx.x;          // b*256 + i == atom index of i
    const int b   = row >> 8;
    const int j   = threadIdx.x;
    const int col = (b << 8) + j;        // atom index of j

    __shared__ unsigned short Zij[256 * ZS];   // 16 KB
    __shared__ unsigned short Zji[256 * ZS];   // 16 KB
    __shared__ float g_lds[256];
    __shared__ float red[4];

    // ---- per-pair scalars (f32x4 ext-vectors, constant-index extracts only)
    const float* ep = e + ((size_t)row * NATOM + j) * 8;
    const f32x4 ea = *(const f32x4*)(ep);
    const f32x4 eb = *(const f32x4*)(ep + 4);
    const float m = mask[row * NATOM + j];
    const float mx = fmaxf(fmaxf(fmaxf(ea[0], ea[1]), fmaxf(ea[2], ea[3])),
                           fmaxf(fmaxf(eb[0], eb[1]), fmaxf(eb[2], eb[3])));
    g_lds[j] = (mx > 1e-5f) ? 0.5f * m : 0.f;

    // ---- layer 1: z_ij/z_ji per k, pack bf16 pairs into swizzled LDS rows
    const float* Pi = P + (size_t)row * 64;   // block-uniform -> s_load
    const float* Pj = P + (size_t)col * 64;   // per-thread vector loads
    const int sw = (j >> 1) & 3;              // this row's chunk swizzle
#pragma unroll
    for (int kq = 0; kq < 8; ++kq) {
        const f32x4 paj = *(const f32x4*)(Pj + kq * 4);
        const f32x4 pbj = *(const f32x4*)(Pj + 32 + kq * 4);
        float zij[4], zji[4];
#pragma unroll
        for (int kk = 0; kk < 4; ++kk) {
            const int k = kq * 4 + kk;
            float ez = 0.f;
#pragma unroll
            for (int de = 0; de < 8; ++de) {
                const float ev = (de < 4) ? ea[de] : eb[de - 4];
                ez += ev * W1[(72 + de) * 32 + k];   // uniform -> s_load
            }
            const float pai = Pi[k];        // uniform
            const float pbi = Pi[32 + k];   // uniform (has b1)
            zij[kk] = fmaxf(pai + pbj[kk] + ez, 0.f);
            zji[kk] = fmaxf(paj[kk] + pbi + ez, 0.f);
        }
        // swizzled store: 16B chunk = kq>>1, chunk' = chunk ^ sw
        const int off = j * ZS + (((kq >> 1) ^ sw) << 3) + ((kq & 1) << 2);
        *(u32x2*)&Zij[off] = (u32x2){ pk2(zij[0], zij[1]), pk2(zij[2], zij[3]) };
        *(u32x2*)&Zji[off] = (u32x2){ pk2(zji[0], zji[1]), pk2(zji[2], zji[3]) };
    }

    // ---- A-fragments: A[m=u=lo][k] = W2[k][lo] (pk2 path, R9-validated)
    const int wave = threadIdx.x >> 6;
    const int lane = threadIdx.x & 63;
    const int lo   = lane & 31;
    const int h    = lane >> 5;
    const int kA   = h * 8;
    const u32x4 a0w = { pk2(W2[(kA + 0) * 32 + lo], W2[(kA + 1) * 32 + lo]),
                        pk2(W2[(kA + 2) * 32 + lo], W2[(kA + 3) * 32 + lo]),
                        pk2(W2[(kA + 4) * 32 + lo], W2[(kA + 5) * 32 + lo]),
                        pk2(W2[(kA + 6) * 32 + lo], W2[(kA + 7) * 32 + lo]) };
    const u32x4 a1w = { pk2(W2[(16 + kA + 0) * 32 + lo], W2[(16 + kA + 1) * 32 + lo]),
                        pk2(W2[(16 + kA + 2) * 32 + lo], W2[(16 + kA + 3) * 32 + lo]),
                        pk2(W2[(16 + kA + 4) * 32 + lo], W2[(16 + kA + 5) * 32 + lo]),
                        pk2(W2[(16 + kA + 6) * 32 + lo], W2[(16 + kA + 7) * 32 + lo]) };
    const bf16x8 A0 = __builtin_bit_cast(bf16x8, a0w);
    const bf16x8 A1 = __builtin_bit_cast(bf16x8, a1w);

    __syncthreads();

    // ---- layer 2 via MFMA: C[u][j'] = sum_k W2t[u][k] * Z[j'][k]
    const int swr = (lo >> 1) & 3;    // read-side swizzle (jt multiple of 32)
    float vacc = 0.f;
#pragma unroll
    for (int nt = 0; nt < 2; ++nt) {
        const int jt = (wave + nt * 4) * 32;     // j-tile base
        const int rbase = (jt + lo) * ZS;
        // chunk = kb*2 + h, swizzled by row
        const int o0 = rbase + (((0 * 2 + h) ^ swr) << 3);   // k: h*8 .. +8
        const int o1 = rbase + (((1 * 2 + h) ^ swr) << 3);   // k: 16+h*8 .. +8
        f32x16 cij = {0.f}, cji = {0.f};
        {
            const bf16x8 bz0 = *(const bf16x8*)&Zij[o0];
            const bf16x8 bz1 = *(const bf16x8*)&Zij[o1];
            cij = __builtin_amdgcn_mfma_f32_32x32x16_bf16(A0, bz0, cij, 0, 0, 0);
            cij = __builtin_amdgcn_mfma_f32_32x32x16_bf16(A1, bz1, cij, 0, 0, 0);
        }
        {
            const bf16x8 bz0 = *(const bf16x8*)&Zji[o0];
            const bf16x8 bz1 = *(const bf16x8*)&Zji[o1];
            cji = __builtin_amdgcn_mfma_f32_32x32x16_bf16(A0, bz0, cji, 0, 0, 0);
            cji = __builtin_amdgcn_mfma_f32_32x32x16_bf16(A1, bz1, cji, 0, 0, 0);
        }
        // epilogue: C col = jt+lo, rows u = (reg&3)+8*(reg>>2)+4h
        float d = 0.f;
#pragma unroll
        for (int reg = 0; reg < 16; ++reg) {
            const int u0 = (reg & 3) + 8 * (reg >> 2);
            const float b2v = h ? b2[u0 + 4] : b2[u0];
            const float w3v = h ? W3[u0 + 4] : W3[u0];
            const float rij = fmaxf(cij[reg] + b2v, 0.f);
            const float rji = fmaxf(cji[reg] + b2v, 0.f);
            d += (rij - rji) * w3v;
        }
        d += __shfl_xor(d, 32, 64);              // complete the 32-u sum
        vacc += d * g_lds[jt + lo];
    }

    // wave sum (each j counted in both halves -> x2), then block sum
#pragma unroll
    for (int off = 1; off < 64; off <<= 1)
        vacc += __shfl_xor(vacc, off, 64);
    if (lane == 0) red[wave] = vacc;
    __syncthreads();
    if (threadIdx.x == 0)
        out[row] = q[row] + 0.5f * (red[0] + red[1] + red[2] + red[3]);
}

extern "C" void kernel_launch(void* const* d_in, const int* in_sizes, int n_in,
                              void* d_out, int out_size, void* d_ws, size_t ws_size,
                              hipStream_t stream)
{
    const float* h    = (const float*)d_in[0];
    const float* e    = (const float*)d_in[1];
    const float* x    = (const float*)d_in[2];
    const float* q    = (const float*)d_in[3];
    const float* mask = (const float*)d_in[4];
    const float* W1   = (const float*)d_in[5];
    const float* b1   = (const float*)d_in[6];
    const float* W2   = (const float*)d_in[7];
    const float* b2   = (const float*)d_in[8];
    const float* W3   = (const float*)d_in[9];
    // b3 cancels in the antisymmetric difference.

    float* P = (float*)d_ws;  // [2048][64] floats = 512 KB

    atom_proj_kernel<<<256, 256, 0, stream>>>(x, h, q, W1, b1, P);
    pair_kernel<<<TOT_ATOMS, 256, 0, stream>>>(e, mask, q, P, W1, W2, b2, W3,
                                               (float*)d_out);
}

// Round 11
// 107.137 us; speedup vs baseline: 2.9439x; 1.2634x over previous
//
#include <hip/hip_runtime.h>

// EPN layer: B=8, N=256, DH=32, DX=3, DQ=1, DE=8, H1=H2=32, DIN=80.
// layer1 = relu(Pa[i] + Pb'[j] + e_ij@W1e), Pb' has b1 folded in.
// b3 cancels in 0.5*(elec_ij - elec_ji).
//
// R1: remat. R3: fission. R5: AGPR accs + spilled atom_proj.
// R6: MFMA layer-2 with LDS-staged Z (ZS=40, W2t in LDS): best total 107.2,
//     pair <= 41us, conflicts 0.
// R7-9: barrier-free k-split: 100-250us, abandoned (codegen pathologies).
// R10: ZS=32+XOR swizzle + A-frags from global W2 gathers: pair 56us,
//     conflicts 262k, total 135. Both "improvements" regressed. REVERTED.
// R11: R6 verbatim + ONE change: ez inner product vectorized as f32x4
//     (s_load_dwordx4 W1 operands, v_pk_fma_f32 lowering), explicit .xyzw
//     element access everywhere (no address-taken locals).

#define NATOM 256
#define TOT_ATOMS 2048
#define ZS 40   // ushort elems per Z row: 80 B = 16B-aligned, 20-bank stride

typedef __bf16 bf16x8 __attribute__((ext_vector_type(8)));
typedef float  f32x16 __attribute__((ext_vector_type(16)));
typedef float  f32x4  __attribute__((ext_vector_type(4)));

__device__ __forceinline__ unsigned int pk2(float a, float b) {
    unsigned short lo = __builtin_bit_cast(unsigned short, (__bf16)a);
    unsigned short hi = __builtin_bit_cast(unsigned short, (__bf16)b);
    return (unsigned int)lo | ((unsigned int)hi << 16);
}

// ---- Kernel A: per-atom projections, P[atom][64]: c<32 = Pa, c>=32 = Pb+b1.
__global__ __launch_bounds__(256) void atom_proj_kernel(
    const float* __restrict__ x, const float* __restrict__ h,
    const float* __restrict__ q, const float* __restrict__ W1,
    const float* __restrict__ b1, float* __restrict__ P)
{
    const int a  = threadIdx.x >> 5;   // 0..7
    const int u  = threadIdx.x & 31;   // 0..31
    const int n0 = blockIdx.x * 8;

    __shared__ float sd[8][37];        // x(3), h(32), q(1), pad
    for (int idx = threadIdx.x; idx < 8 * 36; idx += 256) {
        const int aa = idx / 36, r = idx - aa * 36;
        const int n = n0 + aa;
        float v;
        if (r < 3)       v = x[n * 3 + r];
        else if (r < 35) v = h[n * 32 + (r - 3)];
        else             v = q[n];
        sd[aa][r] = v;
    }
    __syncthreads();

    float pa = 0.f, pb = b1[u];
#pragma unroll
    for (int r = 0; r < 36; ++r) {
        const float d = sd[a][r];
        pa += d * W1[r * 32 + u];
        pb += d * W1[(36 + r) * 32 + u];
    }
    const int n = n0 + a;
    P[(size_t)n * 64 + u]      = pa;
    P[(size_t)n * 64 + 32 + u] = pb;
}

// ---- Kernel B: one block per (b,i) row; VALU layer-1 -> bf16 Z in LDS ->
//      MFMA layer-2 (transposed) -> per-lane layer-3/antisym epilogue.
__global__ __launch_bounds__(256, 3) void pair_kernel(
    const float* __restrict__ e, const float* __restrict__ mask,
    const float* __restrict__ q, const float* __restrict__ P,
    const float* __restrict__ W1, const float* __restrict__ W2,
    const float* __restrict__ b2, const float* __restrict__ W3,
    float* __restrict__ out)
{
    const int row = blockIdx.x;          // b*256 + i == atom index of i
    const int b   = row >> 8;
    const int j   = threadIdx.x;
    const int col = (b << 8) + j;        // atom index of j

    __shared__ unsigned short Zij[256 * ZS];
    __shared__ unsigned short Zji[256 * ZS];
    __shared__ unsigned short W2t[32 * ZS];   // W2t[u][k] = W2[k][u], bf16
    __shared__ float g_lds[256];
    __shared__ float red[4];

    // ---- per-pair scalars
    const float* ep = e + (size_t)(row * NATOM + j) * 8;
    const float4 ev0 = ((const float4*)ep)[0];
    const float4 ev1 = ((const float4*)ep)[1];
    const float m = mask[row * NATOM + j];
    const float mx = fmaxf(fmaxf(fmaxf(ev0.x, ev0.y), fmaxf(ev0.z, ev0.w)),
                           fmaxf(fmaxf(ev1.x, ev1.y), fmaxf(ev1.z, ev1.w)));
    g_lds[j] = (mx > 1e-5f) ? 0.5f * m : 0.f;

    // ---- stage W2^T in bf16 (thread -> 4 entries)
    {
        const int u  = threadIdx.x >> 3;        // 0..31
        const int k0 = (threadIdx.x & 7) * 4;   // 0,4,..,28
        const unsigned int p0 = pk2(W2[(k0 + 0) * 32 + u], W2[(k0 + 1) * 32 + u]);
        const unsigned int p1 = pk2(W2[(k0 + 2) * 32 + u], W2[(k0 + 3) * 32 + u]);
        *(unsigned int*)&W2t[u * ZS + k0]     = p0;
        *(unsigned int*)&W2t[u * ZS + k0 + 2] = p1;
    }

    // ---- layer 1: z_ij/z_ji per k, pack bf16 pairs into LDS
    const float* Pi = P + (size_t)row * 64;   // uniform -> s_load
    const float* Pj = P + (size_t)col * 64;   // per-thread vector loads
#pragma unroll
    for (int kq = 0; kq < 8; ++kq) {
        const float4 paj4 = ((const float4*)Pj)[kq];
        const float4 pbj4 = ((const float4*)Pj)[8 + kq];
        const int k0 = kq * 4;

        // ez[0..3] for k = k0..k0+3, vectorized (W1 rows uniform -> s_load_dwordx4)
        f32x4 ez = {0.f, 0.f, 0.f, 0.f};
        ez += (*(const f32x4*)(W1 + (72 + 0) * 32 + k0)) * ev0.x;
        ez += (*(const f32x4*)(W1 + (72 + 1) * 32 + k0)) * ev0.y;
        ez += (*(const f32x4*)(W1 + (72 + 2) * 32 + k0)) * ev0.z;
        ez += (*(const f32x4*)(W1 + (72 + 3) * 32 + k0)) * ev0.w;
        ez += (*(const f32x4*)(W1 + (72 + 4) * 32 + k0)) * ev1.x;
        ez += (*(const f32x4*)(W1 + (72 + 5) * 32 + k0)) * ev1.y;
        ez += (*(const f32x4*)(W1 + (72 + 6) * 32 + k0)) * ev1.z;
        ez += (*(const f32x4*)(W1 + (72 + 7) * 32 + k0)) * ev1.w;

        const float zij0 = fmaxf(Pi[k0 + 0] + pbj4.x + ez[0], 0.f);
        const float zij1 = fmaxf(Pi[k0 + 1] + pbj4.y + ez[1], 0.f);
        const float zij2 = fmaxf(Pi[k0 + 2] + pbj4.z + ez[2], 0.f);
        const float zij3 = fmaxf(Pi[k0 + 3] + pbj4.w + ez[3], 0.f);
        const float zji0 = fmaxf(paj4.x + Pi[32 + k0 + 0] + ez[0], 0.f);
        const float zji1 = fmaxf(paj4.y + Pi[32 + k0 + 1] + ez[1], 0.f);
        const float zji2 = fmaxf(paj4.z + Pi[32 + k0 + 2] + ez[2], 0.f);
        const float zji3 = fmaxf(paj4.w + Pi[32 + k0 + 3] + ez[3], 0.f);

        *(uint2*)&Zij[j * ZS + k0] = make_uint2(pk2(zij0, zij1), pk2(zij2, zij3));
        *(uint2*)&Zji[j * ZS + k0] = make_uint2(pk2(zji0, zji1), pk2(zji2, zji3));
    }
    __syncthreads();

    // ---- layer 2 via MFMA: C[u][j'] = sum_k W2t[u][k] * Z[j'][k]
    const int wave = threadIdx.x >> 6;
    const int lane = threadIdx.x & 63;
    const int lo = lane & 31;     // = u for A, = j-col for B/C
    const int h  = lane >> 5;     // k-half selector / C row offset

    const bf16x8 a0 = *(const bf16x8*)&W2t[lo * ZS + h * 8];        // k 0..15
    const bf16x8 a1 = *(const bf16x8*)&W2t[lo * ZS + 16 + h * 8];   // k 16..31

    float vacc = 0.f;
#pragma unroll
    for (int nt = 0; nt < 2; ++nt) {
        const int jt = (wave + nt * 4) * 32;     // j-tile base
        const int zo = (jt + lo) * ZS + h * 8;
        f32x16 cij = {0.f}, cji = {0.f};
        {
            const bf16x8 bz0 = *(const bf16x8*)&Zij[zo];
            const bf16x8 bz1 = *(const bf16x8*)&Zij[zo + 16];
            cij = __builtin_amdgcn_mfma_f32_32x32x16_bf16(a0, bz0, cij, 0, 0, 0);
            cij = __builtin_amdgcn_mfma_f32_32x32x16_bf16(a1, bz1, cij, 0, 0, 0);
        }
        {
            const bf16x8 bz0 = *(const bf16x8*)&Zji[zo];
            const bf16x8 bz1 = *(const bf16x8*)&Zji[zo + 16];
            cji = __builtin_amdgcn_mfma_f32_32x32x16_bf16(a0, bz0, cji, 0, 0, 0);
            cji = __builtin_amdgcn_mfma_f32_32x32x16_bf16(a1, bz1, cji, 0, 0, 0);
        }
        // epilogue: per lane, 16 u-values (u = (reg&3)+8*(reg>>2)+4h), col j=jt+lo
        float d = 0.f;
#pragma unroll
        for (int reg = 0; reg < 16; ++reg) {
            const int u0 = (reg & 3) + 8 * (reg >> 2);
            const float b2v = h ? b2[u0 + 4] : b2[u0];
            const float w3v = h ? W3[u0 + 4] : W3[u0];
            const float rij = fmaxf(cij[reg] + b2v, 0.f);
            const float rji = fmaxf(cji[reg] + b2v, 0.f);
            d += (rij - rji) * w3v;
        }
        d += __shfl_xor(d, 32, 64);              // complete the 32-u sum
        vacc += d * g_lds[jt + lo];
    }

    // wave sum (each j counted in both halves -> x2), then block sum
#pragma unroll
    for (int off = 1; off < 64; off <<= 1)
        vacc += __shfl_xor(vacc, off, 64);
    if (lane == 0) red[wave] = vacc;
    __syncthreads();
    if (threadIdx.x == 0)
        out[row] = q[row] + 0.5f * (red[0] + red[1] + red[2] + red[3]);
}

extern "C" void kernel_launch(void* const* d_in, const int* in_sizes, int n_in,
                              void* d_out, int out_size, void* d_ws, size_t ws_size,
                              hipStream_t stream)
{
    const float* h    = (const float*)d_in[0];
    const float* e    = (const float*)d_in[1];
    const float* x    = (const float*)d_in[2];
    const float* q    = (const float*)d_in[3];
    const float* mask = (const float*)d_in[4];
    const float* W1   = (const float*)d_in[5];
    const float* b1   = (const float*)d_in[6];
    const float* W2   = (const float*)d_in[7];
    const float* b2   = (const float*)d_in[8];
    const float* W3   = (const float*)d_in[9];
    // b3 cancels in the antisymmetric difference.

    float* P = (float*)d_ws;  // [2048][64] floats = 512 KB

    atom_proj_kernel<<<256, 256, 0, stream>>>(x, h, q, W1, b1, P);
    pair_kernel<<<TOT_ATOMS, 256, 0, stream>>>(e, mask, q, P, W1, W2, b2, W3,
                                               (float*)d_out);
}

// Round 12
// 106.847 us; speedup vs baseline: 2.9519x; 1.0027x over previous
//
#include <hip/hip_runtime.h>

// EPN layer: B=8, N=256, DH=32, DX=3, DQ=1, DE=8, H1=H2=32, DIN=80.
// layer1 = relu(Pa[i] + Pb'[j] + e_ij@W1e), Pb' has b1 folded in.
// b3 cancels in 0.5*(elec_ij - elec_ji).
//
// R1: remat. R3: fission. R5: AGPR accs. R6: MFMA layer-2, LDS Z (107.2us).
// R7-9: barrier-free k-split regressed (latency-starved gathers). R10: LDS
//   swizzle + global A-frags regressed. R11: ez f32x4 = neutral -> pair is
//   latency/occupancy-bound (3 blocks/CU), not issue-bound.
// R12: exploit elec_ji(row i,col j) == elec_ij(row j,col i): kernel B now
//   computes ONE orientation E[i][j] (+gate G[i][j]) -> half the MLP work,
//   LDS 43.5->22.5KB -> 7 blocks/CU; kernel C does the antisymmetrized
//   reduce with an L3-resident transpose read.

#define NATOM 256
#define TOT_ATOMS 2048
#define ZS 40   // ushort elems per Z row: 80 B = 16B-aligned, 20-bank stride

typedef __bf16 bf16x8 __attribute__((ext_vector_type(8)));
typedef float  f32x16 __attribute__((ext_vector_type(16)));
typedef float  f32x4  __attribute__((ext_vector_type(4)));

__device__ __forceinline__ unsigned int pk2(float a, float b) {
    unsigned short lo = __builtin_bit_cast(unsigned short, (__bf16)a);
    unsigned short hi = __builtin_bit_cast(unsigned short, (__bf16)b);
    return (unsigned int)lo | ((unsigned int)hi << 16);
}

// ---- Kernel A: per-atom projections, P[atom][64]: c<32 = Pa, c>=32 = Pb+b1.
__global__ __launch_bounds__(256) void atom_proj_kernel(
    const float* __restrict__ x, const float* __restrict__ h,
    const float* __restrict__ q, const float* __restrict__ W1,
    const float* __restrict__ b1, float* __restrict__ P)
{
    const int a  = threadIdx.x >> 5;   // 0..7
    const int u  = threadIdx.x & 31;   // 0..31
    const int n0 = blockIdx.x * 8;

    __shared__ float sd[8][37];        // x(3), h(32), q(1), pad
    for (int idx = threadIdx.x; idx < 8 * 36; idx += 256) {
        const int aa = idx / 36, r = idx - aa * 36;
        const int n = n0 + aa;
        float v;
        if (r < 3)       v = x[n * 3 + r];
        else if (r < 35) v = h[n * 32 + (r - 3)];
        else             v = q[n];
        sd[aa][r] = v;
    }
    __syncthreads();

    float pa = 0.f, pb = b1[u];
#pragma unroll
    for (int r = 0; r < 36; ++r) {
        const float d = sd[a][r];
        pa += d * W1[r * 32 + u];
        pb += d * W1[(36 + r) * 32 + u];
    }
    const int n = n0 + a;
    P[(size_t)n * 64 + u]      = pa;
    P[(size_t)n * 64 + 32 + u] = pb;
}

// ---- Kernel B: one block per (b,i) row; computes E[i][j] = elec_ij (one
//      orientation) and gate G[i][j]. VALU layer-1 -> bf16 Zij in LDS ->
//      MFMA layer-2 -> per-lane layer-3 -> E row write.
__global__ __launch_bounds__(256, 4) void elec_kernel(
    const float* __restrict__ e, const float* __restrict__ mask,
    const float* __restrict__ P, const float* __restrict__ W1,
    const float* __restrict__ W2, const float* __restrict__ b2,
    const float* __restrict__ W3, float* __restrict__ E,
    float* __restrict__ G)
{
    const int row = blockIdx.x;          // b*256 + i == atom index of i
    const int b   = row >> 8;
    const int j   = threadIdx.x;
    const int col = (b << 8) + j;        // atom index of j

    __shared__ unsigned short Zij[256 * ZS];   // 20 KB
    __shared__ unsigned short W2t[32 * ZS];    // 2.5 KB: W2t[u][k] = W2[k][u]

    // ---- per-pair scalars; gate goes straight to global G
    const float* ep = e + (size_t)(row * NATOM + j) * 8;
    const float4 ev0 = ((const float4*)ep)[0];
    const float4 ev1 = ((const float4*)ep)[1];
    const float m = mask[row * NATOM + j];
    const float mx = fmaxf(fmaxf(fmaxf(ev0.x, ev0.y), fmaxf(ev0.z, ev0.w)),
                           fmaxf(fmaxf(ev1.x, ev1.y), fmaxf(ev1.z, ev1.w)));
    G[(size_t)row * NATOM + j] = (mx > 1e-5f) ? 0.5f * m : 0.f;

    // ---- stage W2^T in bf16 (thread -> 4 entries)
    {
        const int u  = threadIdx.x >> 3;        // 0..31
        const int k0 = (threadIdx.x & 7) * 4;   // 0,4,..,28
        const unsigned int p0 = pk2(W2[(k0 + 0) * 32 + u], W2[(k0 + 1) * 32 + u]);
        const unsigned int p1 = pk2(W2[(k0 + 2) * 32 + u], W2[(k0 + 3) * 32 + u]);
        *(unsigned int*)&W2t[u * ZS + k0]     = p0;
        *(unsigned int*)&W2t[u * ZS + k0 + 2] = p1;
    }

    // ---- layer 1 (ij orientation only): z = relu(Pa[i] + Pb[j] + e@W1e)
    const float* Pi = P + (size_t)row * 64;   // uniform -> s_load
    const float* Pj = P + (size_t)col * 64;   // per-thread vector loads
#pragma unroll
    for (int kq = 0; kq < 8; ++kq) {
        const float4 pbj4 = ((const float4*)Pj)[8 + kq];
        const int k0 = kq * 4;

        f32x4 ez = {0.f, 0.f, 0.f, 0.f};
        ez += (*(const f32x4*)(W1 + (72 + 0) * 32 + k0)) * ev0.x;
        ez += (*(const f32x4*)(W1 + (72 + 1) * 32 + k0)) * ev0.y;
        ez += (*(const f32x4*)(W1 + (72 + 2) * 32 + k0)) * ev0.z;
        ez += (*(const f32x4*)(W1 + (72 + 3) * 32 + k0)) * ev0.w;
        ez += (*(const f32x4*)(W1 + (72 + 4) * 32 + k0)) * ev1.x;
        ez += (*(const f32x4*)(W1 + (72 + 5) * 32 + k0)) * ev1.y;
        ez += (*(const f32x4*)(W1 + (72 + 6) * 32 + k0)) * ev1.z;
        ez += (*(const f32x4*)(W1 + (72 + 7) * 32 + k0)) * ev1.w;

        const float z0 = fmaxf(Pi[k0 + 0] + pbj4.x + ez[0], 0.f);
        const float z1 = fmaxf(Pi[k0 + 1] + pbj4.y + ez[1], 0.f);
        const float z2 = fmaxf(Pi[k0 + 2] + pbj4.z + ez[2], 0.f);
        const float z3 = fmaxf(Pi[k0 + 3] + pbj4.w + ez[3], 0.f);

        *(uint2*)&Zij[j * ZS + k0] = make_uint2(pk2(z0, z1), pk2(z2, z3));
    }
    __syncthreads();

    // ---- layer 2 via MFMA: C[u][j'] = sum_k W2t[u][k] * Zij[j'][k]
    const int wave = threadIdx.x >> 6;
    const int lane = threadIdx.x & 63;
    const int lo = lane & 31;     // = u for A, = j-col for B/C
    const int h  = lane >> 5;     // k-half selector / C row offset

    const bf16x8 a0 = *(const bf16x8*)&W2t[lo * ZS + h * 8];        // k 0..15
    const bf16x8 a1 = *(const bf16x8*)&W2t[lo * ZS + 16 + h * 8];   // k 16..31

#pragma unroll
    for (int nt = 0; nt < 2; ++nt) {
        const int jt = (wave + nt * 4) * 32;     // j-tile base
        const int zo = (jt + lo) * ZS + h * 8;
        f32x16 cij = {0.f};
        const bf16x8 bz0 = *(const bf16x8*)&Zij[zo];
        const bf16x8 bz1 = *(const bf16x8*)&Zij[zo + 16];
        cij = __builtin_amdgcn_mfma_f32_32x32x16_bf16(a0, bz0, cij, 0, 0, 0);
        cij = __builtin_amdgcn_mfma_f32_32x32x16_bf16(a1, bz1, cij, 0, 0, 0);

        // layer 3: d = sum_u relu(C[u][j'] + b2[u]) * W3[u]
        float d = 0.f;
#pragma unroll
        for (int reg = 0; reg < 16; ++reg) {
            const int u0 = (reg & 3) + 8 * (reg >> 2);
            const float b2v = h ? b2[u0 + 4] : b2[u0];
            const float w3v = h ? W3[u0 + 4] : W3[u0];
            d += fmaxf(cij[reg] + b2v, 0.f) * w3v;
        }
        d += __shfl_xor(d, 32, 64);              // full 32-u sum in both halves
        if (h == 0)
            E[(size_t)row * NATOM + jt + lo] = d; // coalesced 128B per wave
    }
}

// ---- Kernel C: q_i += sum_j G[i][j] * (E[i][j] - E[j][i])
__global__ __launch_bounds__(256) void antisym_kernel(
    const float* __restrict__ q, const float* __restrict__ E,
    const float* __restrict__ G, float* __restrict__ out)
{
    const int row = blockIdx.x;        // b*256 + i
    const int b   = row >> 8;
    const int i   = row & 255;
    const int j   = threadIdx.x;

    const float eij = E[(size_t)row * NATOM + j];                  // coalesced
    const float eji = E[(size_t)((b << 8) + j) * NATOM + i];       // transpose, L3
    const float g   = G[(size_t)row * NATOM + j];                  // coalesced
    float v = g * (eij - eji);

#pragma unroll
    for (int off = 1; off < 64; off <<= 1)
        v += __shfl_xor(v, off, 64);
    __shared__ float red[4];
    if ((threadIdx.x & 63) == 0) red[threadIdx.x >> 6] = v;
    __syncthreads();
    if (threadIdx.x == 0)
        out[row] = q[row] + (red[0] + red[1] + red[2] + red[3]);
}

extern "C" void kernel_launch(void* const* d_in, const int* in_sizes, int n_in,
                              void* d_out, int out_size, void* d_ws, size_t ws_size,
                              hipStream_t stream)
{
    const float* h    = (const float*)d_in[0];
    const float* e    = (const float*)d_in[1];
    const float* x    = (const float*)d_in[2];
    const float* q    = (const float*)d_in[3];
    const float* mask = (const float*)d_in[4];
    const float* W1   = (const float*)d_in[5];
    const float* b1   = (const float*)d_in[6];
    const float* W2   = (const float*)d_in[7];
    const float* b2   = (const float*)d_in[8];
    const float* W3   = (const float*)d_in[9];
    // b3 cancels in the antisymmetric difference.

    float* P = (float*)d_ws;            // [2048][64]        = 512 KB
    float* E = P + 64 * TOT_ATOMS;      // [2048][256]       = 2 MB
    float* G = E + (size_t)TOT_ATOMS * NATOM;  // [2048][256] = 2 MB

    atom_proj_kernel<<<256, 256, 0, stream>>>(x, h, q, W1, b1, P);
    elec_kernel<<<TOT_ATOMS, 256, 0, stream>>>(e, mask, P, W1, W2, b2, W3, E, G);
    antisym_kernel<<<TOT_ATOMS, 256, 0, stream>>>(q, E, G, (float*)d_out);
}